// Round 8
// baseline (91.686 us; speedup 1.0000x reference)
//
#include <hip/hip_runtime.h>
#include <stdint.h>

typedef __attribute__((ext_vector_type(4))) int int4v;
typedef __attribute__((ext_vector_type(4))) float float4v;

#define NB 96
#define SS 1024
#define DD 64
#define TILE_U32 2048        // 8 KB packed image per 128x64 tile
#define NTILES (NB * 8)      // 768 tiles per operand
#define EPSTR 132            // epilogue buffer row stride (floats)
#define EPW (8 * EPSTR)      // per-wave: 8 rows x 132

// Pack byte0 of four int32s (each holding an int8 value) into one dword.
static __device__ __forceinline__ uint32_t pack4(uint32_t a, uint32_t b,
                                                 uint32_t c, uint32_t d) {
    uint32_t lo = __builtin_amdgcn_perm(b, a, 0x00000400u);  // [a0,b0,x,x]
    uint32_t hi = __builtin_amdgcn_perm(d, c, 0x00000400u);  // [c0,d0,x,x]
    return __builtin_amdgcn_perm(hi, lo, 0x05040100u);       // [a0,b0,c0,d0]
}

// Pre-pack int32-widened inputs into swizzled LDS tile images (as R7).
__global__ __launch_bounds__(256) void pack_kernel(
    const int* __restrict__ X, const int* __restrict__ Y,
    uint32_t* __restrict__ Xp, uint32_t* __restrict__ Yp)
{
    const int tid = threadIdx.x;
    const int blk = blockIdx.x;
    if (blk < NTILES) {
        const int* Xa = X + (size_t)blk * (128 * DD);
        uint32_t* dst = Xp + (size_t)blk * TILE_U32;
        #pragma unroll
        for (int i = 0; i < 8; ++i) {
            const int g = tid + 256 * i;
            const int row = g >> 4, kw = g & 15;
            int4v w = *(const int4v*)(Xa + (size_t)g * 4);
            dst[row * 16 + (kw ^ (row & 15))] =
                pack4((uint32_t)w[0], (uint32_t)w[1], (uint32_t)w[2], (uint32_t)w[3]);
        }
    } else {
        __shared__ uint32_t sb[TILE_U32];
        const int t2 = blk - NTILES;
        const int b = t2 >> 3, nt = t2 & 7;
        const int* Yb = Y + (size_t)b * (DD * SS) + nt * 128;
        const int tw = tid & 31;
        const int4v* srcBase = (const int4v*)Yb + tw;
        #pragma unroll
        for (int it = 0; it < 2; ++it) {
            const int kw = (tid >> 5) + 8 * it;
            const int4v* src = srcBase + (size_t)(4 * kw) * (SS / 4);
            int4v r0 = src[0];
            int4v r1 = src[SS / 4];
            int4v r2 = src[2 * (SS / 4)];
            int4v r3 = src[3 * (SS / 4)];
            const int t0 = 4 * tw;
            sb[(t0 + 0) * 16 + (kw ^ ((t0 + 0) & 15))] =
                pack4(r0[0], r1[0], r2[0], r3[0]);
            sb[(t0 + 1) * 16 + (kw ^ ((t0 + 1) & 15))] =
                pack4(r0[1], r1[1], r2[1], r3[1]);
            sb[(t0 + 2) * 16 + (kw ^ ((t0 + 2) & 15))] =
                pack4(r0[2], r1[2], r2[2], r3[2]);
            sb[(t0 + 3) * 16 + (kw ^ ((t0 + 3) & 15))] =
                pack4(r0[3], r1[3], r2[3], r3[3]);
        }
        __syncthreads();
        uint32_t* dst = Yp + (size_t)t2 * TILE_U32;
        ((int4v*)dst)[tid]       = ((const int4v*)sb)[tid];
        ((int4v*)dst)[tid + 256] = ((const int4v*)sb)[tid + 256];
    }
}

// Main: each block computes 128 rows x 512 cols (loop over 4 Y tiles).
// Waves split rows: wave owns 32 rows x 128 cols per Y-tile iteration.
// Epilogue: per-wave 8x132 LDS transpose; each store = 2 rows x 512 B.
__global__ __launch_bounds__(256) void bmm_i8zp_kernel(
    const uint32_t* __restrict__ Xp,
    const uint32_t* __restrict__ Yp,
    const float* __restrict__ azp,
    const float* __restrict__ bzp,
    const float* __restrict__ alp,
    float* __restrict__ out)     // [96][1024][1024] fp32
{
    __shared__ uint32_t sa[TILE_U32];   // packed X image (persistent)
    __shared__ uint32_t sb[TILE_U32];   // packed Y image (per nt-iter)
    __shared__ float    se[4 * EPW];    // per-wave epilogue buffers

    const int tid = threadIdx.x;
    // XCD swizzle: grid 1536 = 8 x 192; each XCD owns 12 whole batches
    const int bid = (blockIdx.x & 7) * 192 + (blockIdx.x >> 3);
    const int b   = bid >> 4;
    const int mt  = (bid >> 1) & 7;
    const int ntg = bid & 1;

    const float az = *azp, bz = *bzp, al = *alp;
    const float czk = az * bz * (float)DD;

    // stage X image (linear copy of pre-swizzled 8 KB)
    {
        const int4v* Ximg = (const int4v*)(Xp + ((size_t)b * 8 + mt) * TILE_U32);
        ((int4v*)sa)[tid]       = Ximg[tid];
        ((int4v*)sa)[tid + 256] = Ximg[tid + 256];
    }
    __syncthreads();

    const int wid  = tid >> 6;
    const int lane = tid & 63;
    const int rr = lane & 15, qq = lane >> 4;

    // A fragments: wave rows = wid*32 .. +32 (2 sub-tiles of 16)
    int4v aF[2];
    #pragma unroll
    for (int m = 0; m < 2; ++m) {
        const int lr = wid * 32 + m * 16 + rr;
        int4v v;
        #pragma unroll
        for (int c = 0; c < 4; ++c)
            v[c] = (int)sa[lr * 16 + ((qq * 4 + c) ^ rr)];
        aF[m] = v;
    }

    const int4v ones = {0x01010101, 0x01010101, 0x01010101, 0x01010101};
    const int4v zero = {0, 0, 0, 0};

    // rowsum_x corrections (fixed across nt iterations)
    float corr[2][4];
    #pragma unroll
    for (int m = 0; m < 2; ++m) {
        int4v rx = __builtin_amdgcn_mfma_i32_16x16x64_i8(aF[m], ones, zero, 0, 0, 0);
        #pragma unroll
        for (int j = 0; j < 4; ++j)
            corr[m][j] = czk - bz * (float)rx[j];
    }

    float* outb = out + (size_t)b * SS * SS;
    float* ew = &se[wid * EPW];
    const size_t ygbase = (size_t)(b * 8 + ntg * 4) * TILE_U32;

    for (int ntc = 0; ntc < 4; ++ntc) {
        __syncthreads();   // all waves done reading previous sb / epilogue
        {
            const int4v* Yimg = (const int4v*)(Yp + ygbase + (size_t)ntc * TILE_U32);
            ((int4v*)sb)[tid]       = Yimg[tid];
            ((int4v*)sb)[tid + 256] = Yimg[tid + 256];
        }
        __syncthreads();

        // B fragments: all 8 col-tiles
        int4v bF[8];
        #pragma unroll
        for (int n = 0; n < 8; ++n) {
            const int t = n * 16 + rr;
            int4v v;
            #pragma unroll
            for (int c = 0; c < 4; ++c)
                v[c] = (int)sb[t * 16 + ((qq * 4 + c) ^ rr)];
            bF[n] = v;
        }
        float cyf[8];
        #pragma unroll
        for (int n = 0; n < 8; ++n) {
            int4v cy = __builtin_amdgcn_mfma_i32_16x16x64_i8(ones, bF[n], zero, 0, 0, 0);
            cyf[n] = az * (float)cy[0];
        }

        const int cbase = ntg * 512 + ntc * 128;
        #pragma unroll
        for (int m = 0; m < 2; ++m) {
            int4v acc[8];
            #pragma unroll
            for (int n = 0; n < 8; ++n)
                acc[n] = __builtin_amdgcn_mfma_i32_16x16x64_i8(aF[m], bF[n], zero, 0, 0, 0);

            const int rbase16 = mt * 128 + wid * 32 + m * 16;
            #pragma unroll
            for (int p = 0; p < 2; ++p) {
                // scatter rows {qq*4 + 2p, qq*4 + 2p+1} -> bufrow qq*2 + jj
                #pragma unroll
                for (int jj = 0; jj < 2; ++jj) {
                    const int j = p * 2 + jj;
                    #pragma unroll
                    for (int n = 0; n < 8; ++n)
                        ew[(qq * 2 + jj) * EPSTR + n * 16 + rr] =
                            ((float)acc[n][j] - cyf[n] + corr[m][j]) * al;
                }
                // readback + store: 2 rows x 512 B contiguous per instruction
                #pragma unroll
                for (int ir = 0; ir < 4; ++ir) {
                    const int r = 2 * ir + (lane >> 5);        // bufrow 0..7
                    const int grow = rbase16 + (r >> 1) * 4 + p * 2 + (r & 1);
                    float4v v = *(const float4v*)&ew[r * EPSTR + (lane & 31) * 4];
                    __builtin_nontemporal_store(
                        v, (float4v*)(outb + (size_t)grow * SS + cbase + (lane & 31) * 4));
                }
            }
        }
    }
}

extern "C" void kernel_launch(void* const* d_in, const int* in_sizes, int n_in,
                              void* d_out, int out_size, void* d_ws, size_t ws_size,
                              hipStream_t stream)
{
    const int* X = (const int*)d_in[0];
    const int* Y = (const int*)d_in[1];
    const float* azp = (const float*)d_in[2];
    const float* bzp = (const float*)d_in[3];
    const float* alp = (const float*)d_in[4];
    float* out = (float*)d_out;

    uint32_t* Xp = (uint32_t*)d_ws;
    uint32_t* Yp = Xp + (size_t)NTILES * TILE_U32;

    hipLaunchKernelGGL(pack_kernel, dim3(2 * NTILES), dim3(256), 0, stream,
                       X, Y, Xp, Yp);
    hipLaunchKernelGGL(bmm_i8zp_kernel, dim3(NB * 8 * 2), dim3(256), 0, stream,
                       Xp, Yp, azp, bzp, alp, out);
}

// Round 9
// 91.371 us; speedup vs baseline: 1.0034x; 1.0034x over previous
//
#include <hip/hip_runtime.h>
#include <stdint.h>

typedef __attribute__((ext_vector_type(4))) int int4v;
typedef __attribute__((ext_vector_type(4))) float float4v;

#define NB 96
#define SS 1024
#define DD 64
#define EPSTRIDE 68          // per-row f32 stride of per-wave epilogue buffer
#define EPW (16 * EPSTRIDE)  // 1088 f32 per wave
#define TILE_U32 2048        // 8 KB packed image per 128x64 tile
#define NTILES (NB * 8)      // 768 tiles per operand

// Pack byte0 of four int32s (each holding an int8 value) into one dword.
static __device__ __forceinline__ uint32_t pack4(uint32_t a, uint32_t b,
                                                 uint32_t c, uint32_t d) {
    uint32_t lo = __builtin_amdgcn_perm(b, a, 0x00000400u);  // [a0,b0,x,x]
    uint32_t hi = __builtin_amdgcn_perm(d, c, 0x00000400u);  // [c0,d0,x,x]
    return __builtin_amdgcn_perm(hi, lo, 0x05040100u);       // [a0,b0,c0,d0]
}

// Pre-pack int32-widened inputs into the exact swizzled LDS tile images.
__global__ __launch_bounds__(256) void pack_kernel(
    const int* __restrict__ X, const int* __restrict__ Y,
    uint32_t* __restrict__ Xp, uint32_t* __restrict__ Yp)
{
    const int tid = threadIdx.x;
    const int blk = blockIdx.x;
    if (blk < NTILES) {
        const int* Xa = X + (size_t)blk * (128 * DD);
        uint32_t* dst = Xp + (size_t)blk * TILE_U32;
        #pragma unroll
        for (int i = 0; i < 8; ++i) {
            const int g = tid + 256 * i;
            const int row = g >> 4, kw = g & 15;
            int4v w = *(const int4v*)(Xa + (size_t)g * 4);
            dst[row * 16 + (kw ^ (row & 15))] =
                pack4((uint32_t)w[0], (uint32_t)w[1], (uint32_t)w[2], (uint32_t)w[3]);
        }
    } else {
        __shared__ uint32_t sb[TILE_U32];
        const int t2 = blk - NTILES;
        const int b = t2 >> 3, nt = t2 & 7;
        const int* Yb = Y + (size_t)b * (DD * SS) + nt * 128;
        const int tw = tid & 31;
        const int4v* srcBase = (const int4v*)Yb + tw;
        #pragma unroll
        for (int it = 0; it < 2; ++it) {
            const int kw = (tid >> 5) + 8 * it;
            const int4v* src = srcBase + (size_t)(4 * kw) * (SS / 4);
            int4v r0 = src[0];
            int4v r1 = src[SS / 4];
            int4v r2 = src[2 * (SS / 4)];
            int4v r3 = src[3 * (SS / 4)];
            const int t0 = 4 * tw;
            sb[(t0 + 0) * 16 + (kw ^ ((t0 + 0) & 15))] =
                pack4(r0[0], r1[0], r2[0], r3[0]);
            sb[(t0 + 1) * 16 + (kw ^ ((t0 + 1) & 15))] =
                pack4(r0[1], r1[1], r2[1], r3[1]);
            sb[(t0 + 2) * 16 + (kw ^ ((t0 + 2) & 15))] =
                pack4(r0[2], r1[2], r2[2], r3[2]);
            sb[(t0 + 3) * 16 + (kw ^ ((t0 + 3) & 15))] =
                pack4(r0[3], r1[3], r2[3], r3[3]);
        }
        __syncthreads();
        uint32_t* dst = Yp + (size_t)t2 * TILE_U32;
        ((int4v*)dst)[tid]       = ((const int4v*)sb)[tid];
        ((int4v*)dst)[tid + 256] = ((const int4v*)sb)[tid + 256];
    }
}

// out[b][s][t] = alpha * ( C - bz*rowsum(x) - az*colsum(y) + 64*az*bz )
// exact int32 via mfma_i32_16x16x64_i8.  (R7 structure, plain stores.)
__global__ __launch_bounds__(256) void bmm_i8zp_kernel(
    const uint32_t* __restrict__ Xp,
    const uint32_t* __restrict__ Yp,
    const float* __restrict__ azp,
    const float* __restrict__ bzp,
    const float* __restrict__ alp,
    float* __restrict__ out)     // [96][1024][1024] fp32
{
    __shared__ union __align__(16) {
        struct { uint32_t a[TILE_U32]; uint32_t b[TILE_U32]; } s;  // 16 KB staging
        float e[4 * EPW];                                          // 17.4 KB epilogue
    } u;

    const int tid = threadIdx.x;
    // XCD-aware swizzle: grid 6144 = 8 XCDs x 768; each XCD owns 12 batches
    const int bid = (blockIdx.x & 7) * 768 + (blockIdx.x >> 3);
    const int b   = bid >> 6;
    const int mt  = (bid >> 3) & 7;
    const int nt  = bid & 7;
    const int rowbase = mt * 128;
    const int colbase = nt * 128;

    const float az = *azp, bz = *bzp, al = *alp;
    const float czk = az * bz * (float)DD;

    // linear copy of pre-swizzled 8 KB images into LDS
    {
        const int4v* Ximg = (const int4v*)(Xp + ((size_t)b * 8 + mt) * TILE_U32);
        const int4v* Yimg = (const int4v*)(Yp + ((size_t)b * 8 + nt) * TILE_U32);
        int4v a0 = Ximg[tid], a1 = Ximg[tid + 256];
        int4v b0 = Yimg[tid], b1 = Yimg[tid + 256];
        ((int4v*)u.s.a)[tid]       = a0;
        ((int4v*)u.s.a)[tid + 256] = a1;
        ((int4v*)u.s.b)[tid]       = b0;
        ((int4v*)u.s.b)[tid + 256] = b1;
    }
    __syncthreads();

    const int wid  = tid >> 6;      // 4 waves, 2x2 over the 128x128 tile
    const int lane = tid & 63;
    const int wm = wid >> 1, wn = wid & 1;
    const int rr = lane & 15, qq = lane >> 4;

    int4v aF[4], bF[4];
    #pragma unroll
    for (int m = 0; m < 4; ++m) {
        const int lr = wm * 64 + m * 16 + rr;
        int4v v;
        #pragma unroll
        for (int c = 0; c < 4; ++c)
            v[c] = (int)u.s.a[lr * 16 + ((qq * 4 + c) ^ (lr & 15))];
        aF[m] = v;
    }
    #pragma unroll
    for (int n = 0; n < 4; ++n) {
        const int t = wn * 64 + n * 16 + rr;
        int4v v;
        #pragma unroll
        for (int c = 0; c < 4; ++c)
            v[c] = (int)u.s.b[t * 16 + ((qq * 4 + c) ^ (t & 15))];
        bF[n] = v;
    }
    __syncthreads();   // all frag reads done; LDS becomes per-wave epilogue bufs

    const int4v ones = {0x01010101, 0x01010101, 0x01010101, 0x01010101};
    const int4v zero = {0, 0, 0, 0};

    float cyf[4];
    #pragma unroll
    for (int n = 0; n < 4; ++n) {
        int4v cy = __builtin_amdgcn_mfma_i32_16x16x64_i8(ones, bF[n], zero, 0, 0, 0);
        cyf[n] = az * (float)cy[0];
    }

    float* outb = out + (size_t)b * SS * SS;
    float* ew = &u.e[wid * EPW];

    #pragma unroll
    for (int m = 0; m < 4; ++m) {
        int4v rx = __builtin_amdgcn_mfma_i32_16x16x64_i8(aF[m], ones, zero, 0, 0, 0);
        int4v acc[4];
        #pragma unroll
        for (int n = 0; n < 4; ++n)
            acc[n] = __builtin_amdgcn_mfma_i32_16x16x64_i8(aF[m], bF[n], zero, 0, 0, 0);

        #pragma unroll
        for (int j = 0; j < 4; ++j) {
            const float corr = czk - bz * (float)rx[j];
            #pragma unroll
            for (int n = 0; n < 4; ++n)
                ew[(qq * 4 + j) * EPSTRIDE + n * 16 + rr] =
                    ((float)acc[n][j] - cyf[n] + corr) * al;
        }
        const int rbase = rowbase + wm * 64 + m * 16;
        const int cbase = colbase + wn * 64;
        #pragma unroll
        for (int i = 0; i < 4; ++i) {
            const int row = (lane >> 3) + 8 * (i >> 1);
            const int col = (lane & 7) * 4 + 32 * (i & 1);
            float4v v = *(const float4v*)&ew[row * EPSTRIDE + col];
            *(float4v*)(outb + (size_t)(rbase + row) * SS + cbase + col) = v;
        }
    }
}

extern "C" void kernel_launch(void* const* d_in, const int* in_sizes, int n_in,
                              void* d_out, int out_size, void* d_ws, size_t ws_size,
                              hipStream_t stream)
{
    const int* X = (const int*)d_in[0];
    const int* Y = (const int*)d_in[1];
    const float* azp = (const float*)d_in[2];
    const float* bzp = (const float*)d_in[3];
    const float* alp = (const float*)d_in[4];
    float* out = (float*)d_out;

    uint32_t* Xp = (uint32_t*)d_ws;
    uint32_t* Yp = Xp + (size_t)NTILES * TILE_U32;

    hipLaunchKernelGGL(pack_kernel, dim3(2 * NTILES), dim3(256), 0, stream,
                       X, Y, Xp, Yp);
    hipLaunchKernelGGL(bmm_i8zp_kernel, dim3(NB * 8 * 8), dim3(256), 0, stream,
                       Xp, Yp, azp, bzp, alp, out);
}

// Round 10
// 84.722 us; speedup vs baseline: 1.0822x; 1.0785x over previous
//
#include <hip/hip_runtime.h>
#include <stdint.h>

typedef __attribute__((ext_vector_type(4))) int int4v;
typedef __attribute__((ext_vector_type(4))) float float4v;

#define NB 96
#define SS 1024
#define DD 64
#define TILE_U32 2048        // 8 KB packed image per 128x64 tile
#define NBT (NB * 8)         // 768 B-tiles
#define NAPACK 1536          // A-compaction blocks (1024 out-dwords each)

// psi: bit-swapped nibble for bank-conflict-free fragment reads
__device__ __forceinline__ int PSI(int r) { return ((r & 3) << 2) | (r >> 2); }

// Pack byte0 of four int32s (each holding an int8 value) into one dword.
static __device__ __forceinline__ uint32_t pack4(uint32_t a, uint32_t b,
                                                 uint32_t c, uint32_t d) {
    uint32_t lo = __builtin_amdgcn_perm(b, a, 0x00000400u);  // [a0,b0,x,x]
    uint32_t hi = __builtin_amdgcn_perm(d, c, 0x00000400u);  // [c0,d0,x,x]
    return __builtin_amdgcn_perm(hi, lo, 0x05040100u);       // [a0,b0,c0,d0]
}

// Xp: plain 4:1 compaction of X (row-major [96*1024][16] dwords).
// Yp: per (b,nt) 8 KB image; image row u holds logical col
//     sigma(u) = (u>>6)*64 + 4*(u&15) + ((u>>4)&3), intra-row dword slot
//     kw ^ PSI(u&15). This bakes the column permutation that makes each
//     lane's 4 accumulators consecutive output columns.
__global__ __launch_bounds__(256) void pack_kernel(
    const int* __restrict__ X, const int* __restrict__ Y,
    uint32_t* __restrict__ Xp, uint32_t* __restrict__ Yp)
{
    const int tid = threadIdx.x;
    const int blk = blockIdx.x;
    if (blk < NAPACK) {
        const int g = blk * 256 + tid;          // out int4v index
        const int4v* src = (const int4v*)X + (size_t)g * 4;
        int4v w0 = src[0], w1 = src[1], w2 = src[2], w3 = src[3];
        int4v o;
        o[0] = (int)pack4((uint32_t)w0[0], (uint32_t)w0[1], (uint32_t)w0[2], (uint32_t)w0[3]);
        o[1] = (int)pack4((uint32_t)w1[0], (uint32_t)w1[1], (uint32_t)w1[2], (uint32_t)w1[3]);
        o[2] = (int)pack4((uint32_t)w2[0], (uint32_t)w2[1], (uint32_t)w2[2], (uint32_t)w2[3]);
        o[3] = (int)pack4((uint32_t)w3[0], (uint32_t)w3[1], (uint32_t)w3[2], (uint32_t)w3[3]);
        ((int4v*)Xp)[g] = o;
    } else {
        __shared__ uint32_t sb[TILE_U32];
        const int t2 = blk - NAPACK;
        const int b = t2 >> 3, nt = t2 & 7;
        const int* Yb = Y + (size_t)b * (DD * SS) + nt * 128;
        const int tw = tid & 31;                // logical col quad (cols 4tw..4tw+3)
        const int r  = tw & 15, wn = tw >> 4;
        const int4v* srcBase = (const int4v*)Yb + tw;
        #pragma unroll
        for (int it = 0; it < 2; ++it) {
            const int kw = (tid >> 5) + 8 * it;
            const int4v* src = srcBase + (size_t)(4 * kw) * (SS / 4);
            int4v r0 = src[0];
            int4v r1 = src[SS / 4];
            int4v r2 = src[2 * (SS / 4)];
            int4v r3 = src[3 * (SS / 4)];
            const int slot = kw ^ PSI(r);
            // logical col 4tw+n -> image row u = wn*64 + n*16 + r
            #pragma unroll
            for (int n = 0; n < 4; ++n) {
                uint32_t pk = pack4((uint32_t)r0[n], (uint32_t)r1[n],
                                    (uint32_t)r2[n], (uint32_t)r3[n]);
                sb[(wn * 64 + n * 16 + r) * 16 + slot] = pk;
            }
        }
        __syncthreads();
        uint32_t* dst = Yp + (size_t)t2 * TILE_U32;
        ((int4v*)dst)[tid]       = ((const int4v*)sb)[tid];
        ((int4v*)dst)[tid + 256] = ((const int4v*)sb)[tid + 256];
    }
}

// out[b][s][t] = alpha * ( C - bz*rowsum(x) - az*colsum(y) + 64*az*bz )
// exact int32 via mfma_i32_16x16x64_i8. Direct nt stores: per instruction
// 4 rows x 256 B contiguous (column permutation baked into Yp).
__global__ __launch_bounds__(256) void bmm_i8zp_kernel(
    const uint32_t* __restrict__ Xp,
    const uint32_t* __restrict__ Yp,
    const float* __restrict__ azp,
    const float* __restrict__ bzp,
    const float* __restrict__ alp,
    float* __restrict__ out)     // [96][1024][1024] fp32
{
    __shared__ uint32_t sb[TILE_U32];   // packed B image only (8 KB)

    const int tid = threadIdx.x;
    // XCD-aware swizzle: grid 6144 = 8 XCDs x 768; each XCD owns 12 batches
    const int bid = (blockIdx.x & 7) * 768 + (blockIdx.x >> 3);
    const int b   = bid >> 6;
    const int mt  = (bid >> 3) & 7;
    const int nt  = bid & 7;
    const int rowbase = mt * 128;
    const int colbase = nt * 128;

    const float az = *azp, bz = *bzp, al = *alp;
    const float czk = az * bz * (float)DD;

    // stage B image (linear 8 KB copy)
    {
        const int4v* Yimg = (const int4v*)(Yp + ((size_t)b * 8 + nt) * TILE_U32);
        ((int4v*)sb)[tid]       = Yimg[tid];
        ((int4v*)sb)[tid + 256] = Yimg[tid + 256];
    }

    const int wid  = tid >> 6;      // 4 waves, 2x2 over the 128x128 tile
    const int lane = tid & 63;
    const int wm = wid >> 1, wn = wid & 1;
    const int rr = lane & 15, qq = lane >> 4;

    // A fragments straight from packed global (1 KB coalesced per instr)
    int4v aF[4];
    {
        const int4v* Ximg = (const int4v*)Xp;
        #pragma unroll
        for (int m = 0; m < 4; ++m)
            aF[m] = Ximg[(size_t)(b * SS + rowbase + wm * 64 + m * 16 + rr) * 4 + qq];
    }
    __syncthreads();

    // B fragments: slot rr of bF[n] = logical col 4rr+n (2-way banks, free)
    int4v bF[4];
    #pragma unroll
    for (int n = 0; n < 4; ++n) {
        const int u = wn * 64 + n * 16 + rr;
        int4v v;
        #pragma unroll
        for (int c = 0; c < 4; ++c)
            v[c] = (int)sb[u * 16 + ((qq * 4 + c) ^ PSI(rr))];
        bF[n] = v;
    }

    const int4v ones = {0x01010101, 0x01010101, 0x01010101, 0x01010101};
    const int4v zero = {0, 0, 0, 0};

    // colsum correction, pre-scaled: aun[n] = al*az*colsum_y[col 4rr+n]
    float aun[4];
    #pragma unroll
    for (int n = 0; n < 4; ++n) {
        int4v cy = __builtin_amdgcn_mfma_i32_16x16x64_i8(ones, bF[n], zero, 0, 0, 0);
        aun[n] = al * az * (float)cy[0];
    }

    float* outb = out + (size_t)b * SS * SS;
    const int cb = colbase + wn * 64 + 4 * rr;

    #pragma unroll
    for (int m = 0; m < 4; ++m) {
        int4v rx = __builtin_amdgcn_mfma_i32_16x16x64_i8(aF[m], ones, zero, 0, 0, 0);
        int4v acc[4];
        #pragma unroll
        for (int n = 0; n < 4; ++n)
            acc[n] = __builtin_amdgcn_mfma_i32_16x16x64_i8(aF[m], bF[n], zero, 0, 0, 0);

        float tj[4];
        #pragma unroll
        for (int j = 0; j < 4; ++j)
            tj[j] = al * (czk - bz * (float)rx[j]);

        const int rb = rowbase + wm * 64 + m * 16 + qq * 4;
        #pragma unroll
        for (int j = 0; j < 4; ++j) {
            float4v v;
            #pragma unroll
            for (int n = 0; n < 4; ++n)
                v[n] = fmaf((float)acc[n][j], al, tj[j] - aun[n]);
            __builtin_nontemporal_store(
                v, (float4v*)(outb + (size_t)(rb + j) * SS + cb));
        }
    }
}

extern "C" void kernel_launch(void* const* d_in, const int* in_sizes, int n_in,
                              void* d_out, int out_size, void* d_ws, size_t ws_size,
                              hipStream_t stream)
{
    const int* X = (const int*)d_in[0];
    const int* Y = (const int*)d_in[1];
    const float* azp = (const float*)d_in[2];
    const float* bzp = (const float*)d_in[3];
    const float* alp = (const float*)d_in[4];
    float* out = (float*)d_out;

    uint32_t* Xp = (uint32_t*)d_ws;                       // 6.3 MB
    uint32_t* Yp = Xp + (size_t)NB * SS * (DD / 4);       // 6.3 MB

    hipLaunchKernelGGL(pack_kernel, dim3(NAPACK + NBT), dim3(256), 0, stream,
                       X, Y, Xp, Yp);
    hipLaunchKernelGGL(bmm_i8zp_kernel, dim3(NB * 8 * 8), dim3(256), 0, stream,
                       Xp, Yp, azp, bzp, alp, out);
}

// Round 11
// 77.116 us; speedup vs baseline: 1.1889x; 1.0986x over previous
//
#include <hip/hip_runtime.h>
#include <stdint.h>

typedef __attribute__((ext_vector_type(4))) int int4v;
typedef __attribute__((ext_vector_type(4))) float float4v;

#define NB 96
#define SS 1024
#define DD 64
#define TILE_U32 2048        // 8 KB packed image per 128x64 tile
#define NBT (NB * 8)         // 768 B-tiles

// psi: bit-swapped nibble for bank-conflict-free fragment reads
__device__ __forceinline__ int PSI(int r) { return ((r & 3) << 2) | (r >> 2); }

// Pack byte0 of four int32s (each holding an int8 value) into one dword.
static __device__ __forceinline__ uint32_t pack4(uint32_t a, uint32_t b,
                                                 uint32_t c, uint32_t d) {
    uint32_t lo = __builtin_amdgcn_perm(b, a, 0x00000400u);  // [a0,b0,x,x]
    uint32_t hi = __builtin_amdgcn_perm(d, c, 0x00000400u);  // [c0,d0,x,x]
    return __builtin_amdgcn_perm(hi, lo, 0x05040100u);       // [a0,b0,c0,d0]
}

// B-only pack: per (b,nt) 8 KB image; image row u holds logical col
// sigma(u) = (u>>6)*64 + 4*(u&15) + ((u>>4)&3), intra-row dword slot
// kw ^ PSI(u&15). Bakes the column permutation that makes each lane's 4
// accumulators consecutive output columns.
__global__ __launch_bounds__(256) void pack_kernel(
    const int* __restrict__ Y, uint32_t* __restrict__ Yp)
{
    __shared__ uint32_t sb[TILE_U32];
    const int tid = threadIdx.x;
    const int t2 = blockIdx.x;
    const int b = t2 >> 3, nt = t2 & 7;
    const int* Yb = Y + (size_t)b * (DD * SS) + nt * 128;
    const int tw = tid & 31;                // logical col quad (cols 4tw..4tw+3)
    const int r  = tw & 15, wn = tw >> 4;
    const int4v* srcBase = (const int4v*)Yb + tw;
    #pragma unroll
    for (int it = 0; it < 2; ++it) {
        const int kw = (tid >> 5) + 8 * it;
        const int4v* src = srcBase + (size_t)(4 * kw) * (SS / 4);
        int4v r0 = src[0];
        int4v r1 = src[SS / 4];
        int4v r2 = src[2 * (SS / 4)];
        int4v r3 = src[3 * (SS / 4)];
        const int slot = kw ^ PSI(r);
        #pragma unroll
        for (int n = 0; n < 4; ++n) {
            uint32_t pk = pack4((uint32_t)r0[n], (uint32_t)r1[n],
                                (uint32_t)r2[n], (uint32_t)r3[n]);
            sb[(wn * 64 + n * 16 + r) * 16 + slot] = pk;
        }
    }
    __syncthreads();
    uint32_t* dst = Yp + (size_t)t2 * TILE_U32;
    ((int4v*)dst)[tid]       = ((const int4v*)sb)[tid];
    ((int4v*)dst)[tid + 256] = ((const int4v*)sb)[tid + 256];
}

// out[b][s][t] = alpha * ( C - bz*rowsum(x) - az*colsum(y) + 64*az*bz )
// exact int32 via mfma_i32_16x16x64_i8. A read raw + packed in-register.
// Direct nt stores: 4 rows x 256 B contiguous per instruction.
__global__ __launch_bounds__(256) void bmm_i8zp_kernel(
    const int* __restrict__ X,          // raw [96][1024][64] int32
    const uint32_t* __restrict__ Yp,
    const float* __restrict__ azp,
    const float* __restrict__ bzp,
    const float* __restrict__ alp,
    float* __restrict__ out)     // [96][1024][1024] fp32
{
    __shared__ uint32_t sb[TILE_U32];   // packed B image only (8 KB)

    const int tid = threadIdx.x;
    // XCD-aware swizzle: grid 6144 = 8 XCDs x 768; each XCD owns 12 batches
    const int bid = (blockIdx.x & 7) * 768 + (blockIdx.x >> 3);
    const int b   = bid >> 6;
    const int mt  = (bid >> 3) & 7;
    const int nt  = bid & 7;
    const int rowbase = mt * 128;
    const int colbase = nt * 128;

    const float az = *azp, bz = *bzp, al = *alp;
    const float czk = az * bz * (float)DD;

    // stage B image (linear 8 KB copy)
    {
        const int4v* Yimg = (const int4v*)(Yp + ((size_t)b * 8 + nt) * TILE_U32);
        ((int4v*)sb)[tid]       = Yimg[tid];
        ((int4v*)sb)[tid + 256] = Yimg[tid + 256];
    }

    const int wid  = tid >> 6;      // 4 waves, 2x2 over the 128x128 tile
    const int lane = tid & 63;
    const int wm = wid >> 1, wn = wid & 1;
    const int rr = lane & 15, qq = lane >> 4;

    // A fragments: raw coalesced-ish dwordx4 loads (L2/L3-resident) + reg pack
    int4v aF[4];
    {
        #pragma unroll
        for (int m = 0; m < 4; ++m) {
            const int4v* arow = (const int4v*)(X +
                (size_t)(b * SS + rowbase + wm * 64 + m * 16 + rr) * DD + qq * 16);
            int4v w0 = arow[0], w1 = arow[1], w2 = arow[2], w3 = arow[3];
            int4v v;
            v[0] = (int)pack4((uint32_t)w0[0], (uint32_t)w0[1], (uint32_t)w0[2], (uint32_t)w0[3]);
            v[1] = (int)pack4((uint32_t)w1[0], (uint32_t)w1[1], (uint32_t)w1[2], (uint32_t)w1[3]);
            v[2] = (int)pack4((uint32_t)w2[0], (uint32_t)w2[1], (uint32_t)w2[2], (uint32_t)w2[3]);
            v[3] = (int)pack4((uint32_t)w3[0], (uint32_t)w3[1], (uint32_t)w3[2], (uint32_t)w3[3]);
            aF[m] = v;
        }
    }
    __syncthreads();

    // B fragments: slot rr of bF[n] = logical col 4rr+n (2-way banks, free)
    int4v bF[4];
    #pragma unroll
    for (int n = 0; n < 4; ++n) {
        const int u = wn * 64 + n * 16 + rr;
        int4v v;
        #pragma unroll
        for (int c = 0; c < 4; ++c)
            v[c] = (int)sb[u * 16 + ((qq * 4 + c) ^ PSI(rr))];
        bF[n] = v;
    }

    const int4v ones = {0x01010101, 0x01010101, 0x01010101, 0x01010101};
    const int4v zero = {0, 0, 0, 0};

    // colsum correction (exact integer-valued float): az*colsum_y[col 4rr+n]
    float cyI[4];
    #pragma unroll
    for (int n = 0; n < 4; ++n) {
        int4v cy = __builtin_amdgcn_mfma_i32_16x16x64_i8(ones, bF[n], zero, 0, 0, 0);
        cyI[n] = az * (float)cy[0];
    }

    float* outb = out + (size_t)b * SS * SS;
    const int cb = colbase + wn * 64 + 4 * rr;

    #pragma unroll
    for (int m = 0; m < 4; ++m) {
        int4v rx = __builtin_amdgcn_mfma_i32_16x16x64_i8(aF[m], ones, zero, 0, 0, 0);
        int4v acc[4];
        #pragma unroll
        for (int n = 0; n < 4; ++n)
            acc[n] = __builtin_amdgcn_mfma_i32_16x16x64_i8(aF[m], bF[n], zero, 0, 0, 0);

        const int rb = rowbase + wm * 64 + m * 16 + qq * 4;
        #pragma unroll
        for (int j = 0; j < 4; ++j) {
            const float corr = czk - bz * (float)rx[j];   // exact int
            float4v v;
            #pragma unroll
            for (int n = 0; n < 4; ++n)
                v[n] = ((float)acc[n][j] - cyI[n] + corr) * al;  // exact bracket
            __builtin_nontemporal_store(
                v, (float4v*)(outb + (size_t)(rb + j) * SS + cb));
        }
    }
}

extern "C" void kernel_launch(void* const* d_in, const int* in_sizes, int n_in,
                              void* d_out, int out_size, void* d_ws, size_t ws_size,
                              hipStream_t stream)
{
    const int* X = (const int*)d_in[0];
    const int* Y = (const int*)d_in[1];
    const float* azp = (const float*)d_in[2];
    const float* bzp = (const float*)d_in[3];
    const float* alp = (const float*)d_in[4];
    float* out = (float*)d_out;

    uint32_t* Yp = (uint32_t*)d_ws;                       // 6.3 MB

    hipLaunchKernelGGL(pack_kernel, dim3(NBT), dim3(256), 0, stream, Y, Yp);
    hipLaunchKernelGGL(bmm_i8zp_kernel, dim3(NB * 8 * 8), dim3(256), 0, stream,
                       X, Yp, azp, bzp, alp, out);
}